// Round 10
// baseline (519.139 us; speedup 1.0000x reference)
//
#include <hip/hip_runtime.h>
#include <math.h>

#define S_TOT 8192
#define DD 256
#define NHEAD 8
#define HDSZ 32
#define ATT_SCALE 0.17677669529663687f
#define ATT_SCALE_LOG2E 0.25506601f   // ATT_SCALE * log2(e)

typedef short short8 __attribute__((ext_vector_type(8)));
typedef float f32x4 __attribute__((ext_vector_type(4)));
typedef unsigned short ushort;

// wbuf offsets (ushort elements)
#define OFF_PROJ 0
#define OFF_WQ0  393216
#define OFF_WK0  458752
#define OFF_WV0  524288
#define OFF_WO0  589824
#define OFF_W10  655360
#define OFF_W20  917504
#define OFF_WK1  1179648
#define OFF_WV1  1245184
#define OFF_WQ1  1310720
#define OFF_WO1  1376256
#define OFF_W11  1441792
#define OFF_W21  1703936
#define WBUF_TOT 1966080

__device__ inline ushort f2bf(float f) {
    union { float f; unsigned u; } c; c.f = f;
    unsigned u = c.u;
    u += 0x7fffu + ((u >> 16) & 1u);          // RNE
    return (ushort)(u >> 16);
}
__device__ inline float bf2f(ushort u) {
    union { unsigned u; float f; } c; c.u = ((unsigned)u) << 16;
    return c.f;
}
__device__ inline float gelu_exact(float v) {
    return 0.5f * v * (1.0f + erff(v * 0.7071067811865475f));
}
__device__ inline float block_sum256(float v, float* red) {
    #pragma unroll
    for (int off = 32; off > 0; off >>= 1) v += __shfl_down(v, off, 64);
    const int wid = threadIdx.x >> 6, lane = threadIdx.x & 63;
    if (lane == 0) red[wid] = v;
    __syncthreads();
    const float s = red[0] + red[1] + red[2] + red[3];
    __syncthreads();
    return s;
}

// ============ setup: weight transposes + bias concat + x->bf16 + cls ============
__global__ __launch_bounds__(256)
void setup_kernel(const float* __restrict__ x, const float* __restrict__ proj_w,
                  const float* __restrict__ Wq, const float* __restrict__ Wk,
                  const float* __restrict__ Wv, const float* __restrict__ Wo,
                  const float* __restrict__ W1, const float* __restrict__ W2,
                  const float* __restrict__ bq, const float* __restrict__ bk,
                  const float* __restrict__ bv, const float* __restrict__ cls_tok,
                  ushort* __restrict__ wbuf, float* __restrict__ bqkv0,
                  float* __restrict__ bkv1, ushort* __restrict__ xbf,
                  float* __restrict__ h)
{
    const int b = blockIdx.x;
    const int t = threadIdx.x;
    if (b >= 482) {
        if (b == 6626) { h[t] = cls_tok[t]; return; }   // cls (tab[0]==0)
        const int i = (b - 482) * 256 + t;
        const int n8 = 8191 * 1536 / 8;
        if (i >= n8) return;
        const float4 a0 = *(const float4*)(x + (size_t)i * 8);
        const float4 a1 = *(const float4*)(x + (size_t)i * 8 + 4);
        ushort tmp[8] = { f2bf(a0.x), f2bf(a0.y), f2bf(a0.z), f2bf(a0.w),
                          f2bf(a1.x), f2bf(a1.y), f2bf(a1.z), f2bf(a1.w) };
        *(uint4*)(xbf + (size_t)i * 8) = *(const uint4*)tmp;
        return;
    }
    if (b >= 480) {
        if (b == 480) {
            for (int i = t; i < 768; i += 256)
                bqkv0[i] = (i < 256) ? bq[i] : ((i < 512) ? bk[i - 256] : bv[i - 512]);
        } else {
            for (int i = t; i < 512; i += 256)
                bkv1[i] = (i < 256) ? bk[256 + i] : bv[i];
        }
        return;
    }
    const float* src; ushort* dst; int R, C, t0;
    if (b < 96)       { src = proj_w;        dst = wbuf + OFF_PROJ; R = 1536; C = 256;  t0 = 0;   }
    else if (b < 112) { src = Wq;            dst = wbuf + OFF_WQ0;  R = 256;  C = 256;  t0 = 96;  }
    else if (b < 128) { src = Wk;            dst = wbuf + OFF_WK0;  R = 256;  C = 256;  t0 = 112; }
    else if (b < 144) { src = Wv;            dst = wbuf + OFF_WV0;  R = 256;  C = 256;  t0 = 128; }
    else if (b < 160) { src = Wo;            dst = wbuf + OFF_WO0;  R = 256;  C = 256;  t0 = 144; }
    else if (b < 224) { src = W1;            dst = wbuf + OFF_W10;  R = 256;  C = 1024; t0 = 160; }
    else if (b < 288) { src = W2;            dst = wbuf + OFF_W20;  R = 1024; C = 256;  t0 = 224; }
    else if (b < 304) { src = Wk + 65536;    dst = wbuf + OFF_WK1;  R = 256;  C = 256;  t0 = 288; }
    else if (b < 320) { src = Wv + 65536;    dst = wbuf + OFF_WV1;  R = 256;  C = 256;  t0 = 304; }
    else if (b < 336) { src = Wq + 65536;    dst = wbuf + OFF_WQ1;  R = 256;  C = 256;  t0 = 320; }
    else if (b < 352) { src = Wo + 65536;    dst = wbuf + OFF_WO1;  R = 256;  C = 256;  t0 = 336; }
    else if (b < 416) { src = W1 + 262144;   dst = wbuf + OFF_W11;  R = 256;  C = 1024; t0 = 352; }
    else              { src = W2 + 262144;   dst = wbuf + OFF_W21;  R = 1024; C = 256;  t0 = 416; }
    const int lt = b - t0;
    const int tC = C >> 6;
    const int tr = lt / tC, tc = lt % tC;
    __shared__ ushort tile[64][68];
    const int col = t & 63;
    const int r4  = t >> 6;
    #pragma unroll
    for (int i = 0; i < 16; ++i) {
        const int row = i * 4 + r4;
        tile[row][col] = f2bf(src[(size_t)(tr * 64 + row) * C + tc * 64 + col]);
    }
    __syncthreads();
    #pragma unroll
    for (int i = 0; i < 16; ++i) {
        const int n = i * 4 + r4;
        dst[(size_t)(tc * 64 + n) * R + tr * 64 + col] = tile[col][n];
    }
}

// ============ LayerNorm over D=256, one block per row, bf16 out ============
__global__ __launch_bounds__(256)
void ln_kernel(const float* __restrict__ in, const float* __restrict__ g,
               const float* __restrict__ b, ushort* __restrict__ outp)
{
    __shared__ float red[4];
    const int row = blockIdx.x;
    const int d = threadIdx.x;
    const float xv = in[(size_t)row * DD + d];
    const float mu = block_sum256(xv, red) * (1.0f / 256.0f);
    const float dv = xv - mu;
    const float var = block_sum256(dv * dv, red) * (1.0f / 256.0f);
    outp[(size_t)row * DD + d] = f2bf(dv * rsqrtf(var + 1e-5f) * g[d] + b[d]);
}

// ============ gemm3: BM=128 x BN=64, BK=64, XCD-swizzled 1-D grid ============
// C = [C +] act(A @ Bt^T + bias) [+ pos].  A bf16 MxK, Bt bf16 NxK.
// 4 waves (2x2): wave tile 64x32 = 4x2 MFMAs. LDS 27.6 KB -> 5 blocks/CU.
// flags: 1 = acc into fp32 C, 2 = GELU, 4 = bf16 out, 8 = pos-embed.
// grid = (M_pad/128) * (N/64); M_pad/128 must be divisible by 8.
__global__ __launch_bounds__(256)
void gemm3_kernel(const ushort* __restrict__ A, const ushort* __restrict__ Bt,
                  const float* __restrict__ bias, void* __restrict__ Cv,
                  int M, int N, int K, int flags, const int* __restrict__ coords)
{
    __shared__ ushort As[128][72];
    __shared__ ushort Bs[64][72];
    const int nx  = N >> 6;
    const int ny8 = gridDim.x / (8 * nx);      // m-slabs per XCD
    const int b   = blockIdx.x;
    const int c8  = b & 7;
    const int j   = b >> 3;
    const int m0  = (c8 * ny8 + j / nx) * 128;
    const int n0  = (j % nx) * 64;

    const int tid  = threadIdx.x;
    const int wave = tid >> 6;
    const int lane = tid & 63;
    const int lrow = lane & 15;
    const int quad = lane >> 4;
    const int wr = (wave >> 1) * 64;           // {0,64}
    const int wc = (wave & 1) * 32;            // {0,32}

    float* Cf  = (float*)Cv;
    ushort* Cb = (ushort*)Cv;

    f32x4 acc[4][2];
    #pragma unroll
    for (int mt = 0; mt < 4; ++mt)
        #pragma unroll
        for (int nt = 0; nt < 2; ++nt)
            acc[mt][nt] = (f32x4){0.f, 0.f, 0.f, 0.f};

    for (int kk = 0; kk < K; kk += 64) {
        #pragma unroll
        for (int i = 0; i < 4; ++i) {          // A: 128 rows x 64 cols
            const int idx = i * 256 + tid;
            const int r = idx >> 3;
            const int c = (idx & 7) * 8;
            const int gr = m0 + r;
            uint4 val = make_uint4(0u, 0u, 0u, 0u);
            if (gr < M) val = *(const uint4*)(A + (size_t)gr * K + kk + c);
            *(uint4*)&As[r][c] = val;
        }
        #pragma unroll
        for (int i = 0; i < 2; ++i) {          // B: 64 rows x 64 cols
            const int idx = i * 256 + tid;
            const int r = idx >> 3;
            const int c = (idx & 7) * 8;
            *(uint4*)&Bs[r][c] = *(const uint4*)(Bt + (size_t)(n0 + r) * K + kk + c);
        }
        __syncthreads();
        #pragma unroll
        for (int ks = 0; ks < 2; ++ks) {
            short8 af[4], bfr[2];
            #pragma unroll
            for (int mt = 0; mt < 4; ++mt)
                af[mt] = *(const short8*)&As[wr + mt * 16 + lrow][ks * 32 + quad * 8];
            #pragma unroll
            for (int nt = 0; nt < 2; ++nt)
                bfr[nt] = *(const short8*)&Bs[wc + nt * 16 + lrow][ks * 32 + quad * 8];
            #pragma unroll
            for (int mt = 0; mt < 4; ++mt)
                #pragma unroll
                for (int nt = 0; nt < 2; ++nt)
                    acc[mt][nt] = __builtin_amdgcn_mfma_f32_16x16x32_bf16(
                                      af[mt], bfr[nt], acc[mt][nt], 0, 0, 0);
        }
        __syncthreads();
    }
    #pragma unroll
    for (int mt = 0; mt < 4; ++mt) {
        #pragma unroll
        for (int rg = 0; rg < 4; ++rg) {
            const int r = m0 + wr + mt * 16 + quad * 4 + rg;
            if (r >= M) continue;
            #pragma unroll
            for (int nt = 0; nt < 2; ++nt) {
                const int c = n0 + wc + nt * 16 + lrow;
                float vv = acc[mt][nt][rg] + bias[c];
                if (flags & 8) {   // pos-embed for token r (output = h row r+1)
                    const int cg = coords[2 * r + ((c < 128) ? 1 : 0)] >> 8;
                    const float omega = 1.0f / powf(10000.0f, (float)(c & 63) * (1.0f / 64.0f));
                    const float o = (float)cg * omega;
                    vv += ((c & 64) == 0) ? sinf(o) : cosf(o);
                }
                if (flags & 2) vv = gelu_exact(vv);
                if (flags & 4) {
                    Cb[(size_t)r * N + c] = f2bf(vv);
                } else {
                    if (flags & 1) vv += Cf[(size_t)r * N + c];
                    Cf[(size_t)r * N + c] = vv;
                }
            }
        }
    }
}

// ============ MFMA dilated attention (bf16, no-max softmax) ============
__global__ __launch_bounds__(256)
void attn_mfma_kernel(const ushort* __restrict__ q, const ushort* __restrict__ k,
                      const ushort* __restrict__ v, float* __restrict__ bo5,
                      float* __restrict__ lse5, int qs)
{
    __shared__ ushort Kb[64][40];
    __shared__ ushort Vt[32][72];
    __shared__ ushort Pb[4][16][72];

    const int unit = blockIdx.x;
    const int segu = unit >> 3;
    const int head = unit & 7;
    int b2, n;
    if (segu < 8)        { b2 = 0; n = segu; }
    else if (segu < 12)  { b2 = 1; n = segu - 8; }
    else if (segu < 14)  { b2 = 2; n = segu - 12; }
    else if (segu == 14) { b2 = 3; n = 0; }
    else                 { b2 = 4; n = 0; }
    const int w  = 1024 << b2;
    const int rr = 1 << b2;
    const int base = n * w + (head & (rr - 1));

    int kEnd = (S_TOT - base + rr - 1) >> b2;
    if (kEnd > 1024) kEnd = 1024;
    if (blockIdx.y * 128 >= kEnd) return;

    const int tid  = threadIdx.x;
    const int wave = tid >> 6;
    const int lane = tid & 63;
    const int lrow = lane & 15;
    const int quad = lane >> 4;

    short8 qf[2];
    #pragma unroll
    for (int m = 0; m < 2; ++m) {
        const int j  = blockIdx.y * 128 + wave * 32 + m * 16 + lrow;
        const int pq = base + rr * j;
        qf[m] = *(const short8*)(q + (size_t)pq * qs + head * HDSZ + quad * 8);
    }

    f32x4 acc[2][2];
    float lsum[2][4];
    #pragma unroll
    for (int m = 0; m < 2; ++m) {
        #pragma unroll
        for (int dt = 0; dt < 2; ++dt) acc[m][dt] = (f32x4){0.f, 0.f, 0.f, 0.f};
        #pragma unroll
        for (int rg = 0; rg < 4; ++rg) lsum[m][rg] = 0.f;
    }

    const int skr = tid >> 2;          // 0..63
    const int sdb = (tid & 3) * 8;     // 0,8,16,24

    for (int kc = 0; kc < kEnd; kc += 64) {
        {
            const size_t prow = (size_t)(base + rr * (kc + skr)) * qs + head * HDSZ + sdb;
            *(uint4*)&Kb[skr][sdb] = *(const uint4*)(k + prow);
            const uint4 vv = *(const uint4*)(v + prow);
            const ushort* vp = (const ushort*)&vv;
            #pragma unroll
            for (int i = 0; i < 8; ++i) Vt[sdb + i][skr] = vp[i];   // static index
        }
        __syncthreads();

        short8 kf[4], vf[2][2];
        #pragma unroll
        for (int t = 0; t < 4; ++t)
            kf[t] = *(const short8*)&Kb[t * 16 + lrow][quad * 8];
        #pragma unroll
        for (int g = 0; g < 2; ++g)
            #pragma unroll
            for (int dt = 0; dt < 2; ++dt)
                vf[g][dt] = *(const short8*)&Vt[dt * 16 + lrow][g * 32 + quad * 8];

        #pragma unroll
        for (int m = 0; m < 2; ++m) {
            f32x4 sc[4];
            #pragma unroll
            for (int t = 0; t < 4; ++t)
                sc[t] = __builtin_amdgcn_mfma_f32_16x16x32_bf16(
                            qf[m], kf[t], (f32x4){0.f,0.f,0.f,0.f}, 0, 0, 0);
            float p[4][4];
            #pragma unroll
            for (int t = 0; t < 4; ++t)
                #pragma unroll
                for (int rg = 0; rg < 4; ++rg)
                    p[t][rg] = exp2f(sc[t][rg] * ATT_SCALE_LOG2E);
            #pragma unroll
            for (int rg = 0; rg < 4; ++rg)
                lsum[m][rg] += (p[0][rg] + p[1][rg]) + (p[2][rg] + p[3][rg]);
            #pragma unroll
            for (int t = 0; t < 4; ++t)
                #pragma unroll
                for (int rg = 0; rg < 4; ++rg)
                    Pb[wave][quad * 4 + rg][t * 16 + lrow] = f2bf(p[t][rg]);
            __threadfence_block();
            short8 pa[2];
            #pragma unroll
            for (int g = 0; g < 2; ++g)
                pa[g] = *(const short8*)&Pb[wave][lrow][g * 32 + quad * 8];
            #pragma unroll
            for (int g = 0; g < 2; ++g)
                #pragma unroll
                for (int dt = 0; dt < 2; ++dt)
                    acc[m][dt] = __builtin_amdgcn_mfma_f32_16x16x32_bf16(
                                     pa[g], vf[g][dt], acc[m][dt], 0, 0, 0);
        }
        __syncthreads();
    }

    #pragma unroll
    for (int m = 0; m < 2; ++m) {
        #pragma unroll
        for (int rg = 0; rg < 4; ++rg) {
            float li = lsum[m][rg];
            #pragma unroll
            for (int off = 1; off < 16; off <<= 1)
                li += __shfl_xor(li, off, 16);
            const int j  = blockIdx.y * 128 + wave * 32 + m * 16 + quad * 4 + rg;
            const int pq = base + rr * j;
            const float inv = 1.0f / li;
            float* dst = bo5 + ((size_t)b2 * S_TOT + pq) * DD + head * HDSZ;
            dst[lrow]      = acc[m][0][rg] * inv;
            dst[16 + lrow] = acc[m][1][rg] * inv;
            if (lrow == 0)
                lse5[((size_t)b2 * S_TOT + pq) * NHEAD + head] = __logf(li);
        }
    }
}

// ============ layer-1 pruned attention: query position 0 only ============
__global__ __launch_bounds__(64)
void attn_row0_kernel(const float* __restrict__ q, const ushort* __restrict__ k,
                      const ushort* __restrict__ v, float* __restrict__ bo5,
                      float* __restrict__ lse5, int kvs)
{
    const int b2 = blockIdx.x >> 3;
    const int head = blockIdx.x & 7;
    const int r = 1 << b2;
    if (head & (r - 1)) return;
    const int tid = threadIdx.x;
    float qreg[32];
    #pragma unroll
    for (int d = 0; d < 32; d += 4) {
        const float4 t4 = *(const float4*)(q + head * HDSZ + d);
        qreg[d] = t4.x; qreg[d+1] = t4.y; qreg[d+2] = t4.z; qreg[d+3] = t4.w;
    }
    float m = -3.0e38f, l = 0.f, o[32];
    #pragma unroll
    for (int d = 0; d < 32; ++d) o[d] = 0.f;
    for (int j = tid; j < 1024; j += 64) {
        const int pk = r * j;
        float s;
        if (pk < S_TOT) {
            float s0 = 0.f;
            #pragma unroll
            for (int d = 0; d < 32; d += 8) {
                const uint4 raw = *(const uint4*)(k + (size_t)pk * kvs + head * HDSZ + d);
                const ushort* kp = (const ushort*)&raw;
                #pragma unroll
                for (int i = 0; i < 8; ++i) s0 += qreg[d + i] * bf2f(kp[i]);
            }
            s = s0 * ATT_SCALE;
        } else s = -1.0e9f;
        const float mn = fmaxf(m, s);
        const float c = __expf(m - mn);
        const float e = __expf(s - mn);
        l = l * c + e; m = mn;
        if (pk < S_TOT) {
            #pragma unroll
            for (int d = 0; d < 32; d += 8) {
                const uint4 raw = *(const uint4*)(v + (size_t)pk * kvs + head * HDSZ + d);
                const ushort* vp = (const ushort*)&raw;
                #pragma unroll
                for (int i = 0; i < 8; ++i) o[d + i] = o[d + i] * c + e * bf2f(vp[i]);
            }
        } else {
            #pragma unroll
            for (int d = 0; d < 32; ++d) o[d] *= c;
        }
    }
    __shared__ float ms[64], ls[64], os[64][32];
    ms[tid] = m; ls[tid] = l;
    #pragma unroll
    for (int d = 0; d < 32; ++d) os[tid][d] = o[d];
    __syncthreads();
    for (int st = 32; st >= 1; st >>= 1) {
        if (tid < st) {
            const float m2 = ms[tid + st], l2 = ls[tid + st];
            const float mn = fmaxf(ms[tid], m2);
            const float c1 = __expf(ms[tid] - mn);
            const float c2 = __expf(m2 - mn);
            ls[tid] = ls[tid] * c1 + l2 * c2;
            ms[tid] = mn;
            for (int d = 0; d < 32; ++d) os[tid][d] = os[tid][d]*c1 + os[tid+st][d]*c2;
        }
        __syncthreads();
    }
    if (tid < 32) bo5[(size_t)b2 * S_TOT * DD + head * HDSZ + tid] = os[0][tid] / ls[0];
    if (tid == 0) lse5[(size_t)b2 * S_TOT * NHEAD + head] = ms[0] + __logf(ls[0]);
}

// ============ combine 5 branches (layer 0), bf16 out ============
__global__ __launch_bounds__(256)
void combine_kernel(const float* __restrict__ bo5, const float* __restrict__ lse5,
                    ushort* __restrict__ attn)
{
    const int p = blockIdx.x;
    const int d = threadIdx.x;
    const int h = d >> 5;
    float lse[5];
    bool sel[5];
    float mx = -3.0e38f;
    #pragma unroll
    for (int b2 = 0; b2 < 5; ++b2) {
        const int r = 1 << b2;
        sel[b2] = ((p & (r - 1)) == (h & (r - 1)));
        if (sel[b2]) {
            lse[b2] = lse5[((size_t)b2 * S_TOT + p) * NHEAD + h];
            mx = fmaxf(mx, lse[b2]);
        }
    }
    float wsum = 0.f, acc = 0.f;
    #pragma unroll
    for (int b2 = 0; b2 < 5; ++b2) {
        if (sel[b2]) {
            const float wgt = __expf(lse[b2] - mx);
            wsum += wgt;
            acc += wgt * bo5[((size_t)b2 * S_TOT + p) * DD + d];
        }
    }
    attn[(size_t)p * DD + d] = f2bf(acc / wsum);
}

// ============ tail kernels (row 0 only) ============
__global__ __launch_bounds__(256)
void tail_qrow_kernel(const float* __restrict__ h, const float* __restrict__ g,
                      const float* __restrict__ b, const ushort* __restrict__ Wt,
                      const float* __restrict__ bias, float* __restrict__ qrow0)
{
    __shared__ float red[4];
    __shared__ float as[256];
    const int d = threadIdx.x;
    const float xv = h[d];
    const float mu = block_sum256(xv, red) * (1.0f / 256.0f);
    const float dv = xv - mu;
    const float var = block_sum256(dv * dv, red) * (1.0f / 256.0f);
    as[d] = dv * rsqrtf(var + 1e-5f) * g[d] + b[d];
    __syncthreads();
    float acc = 0.f;
    for (int k2 = 0; k2 < 256; k2 += 8) {
        const short8 w8 = *(const short8*)&Wt[(size_t)d * 256 + k2];
        #pragma unroll
        for (int j = 0; j < 8; ++j) acc += as[k2 + j] * bf2f((ushort)w8[j]);
    }
    qrow0[d] = acc + bias[d];
}

__global__ __launch_bounds__(256)
void tail_mid_kernel(const float* __restrict__ bo5, const float* __restrict__ lse5,
                     float* __restrict__ h, const ushort* __restrict__ Wo1t,
                     const float* __restrict__ bo1, const float* __restrict__ g2,
                     const float* __restrict__ b2, float* __restrict__ f)
{
    __shared__ float red[4];
    __shared__ float att[256];
    const int d = threadIdx.x;
    const int hh = d >> 5;
    float lse[5]; bool sel[5]; float mx = -3.0e38f;
    #pragma unroll
    for (int bb = 0; bb < 5; ++bb) {
        const int r = 1 << bb;
        sel[bb] = ((hh & (r - 1)) == 0);
        if (sel[bb]) {
            lse[bb] = lse5[(size_t)bb * S_TOT * NHEAD + hh];
            mx = fmaxf(mx, lse[bb]);
        }
    }
    float wsum = 0.f, acc = 0.f;
    #pragma unroll
    for (int bb = 0; bb < 5; ++bb) {
        if (sel[bb]) {
            const float wgt = __expf(lse[bb] - mx);
            wsum += wgt;
            acc += wgt * bo5[(size_t)bb * S_TOT * DD + d];
        }
    }
    att[d] = acc / wsum;
    __syncthreads();
    float a2 = 0.f;
    for (int k2 = 0; k2 < 256; k2 += 8) {
        const short8 w8 = *(const short8*)&Wo1t[(size_t)d * 256 + k2];
        #pragma unroll
        for (int j = 0; j < 8; ++j) a2 += att[k2 + j] * bf2f((ushort)w8[j]);
    }
    const float hv = a2 + bo1[d] + h[d];
    h[d] = hv;
    const float mu = block_sum256(hv, red) * (1.0f / 256.0f);
    const float dv = hv - mu;
    const float var = block_sum256(dv * dv, red) * (1.0f / 256.0f);
    f[d] = dv * rsqrtf(var + 1e-5f) * g2[d] + b2[d];
}

__global__ __launch_bounds__(256)
void tail_ffn1_kernel(const float* __restrict__ f, const ushort* __restrict__ W11t,
                      const float* __restrict__ b11, float* __restrict__ midr0)
{
    __shared__ float fs[256];
    const int tid = threadIdx.x;
    fs[tid] = f[tid];
    __syncthreads();
    const int n = blockIdx.x * 256 + tid;
    float acc = 0.f;
    for (int k2 = 0; k2 < 256; k2 += 8) {
        const short8 w8 = *(const short8*)&W11t[(size_t)n * 256 + k2];
        #pragma unroll
        for (int j = 0; j < 8; ++j) acc += fs[k2 + j] * bf2f((ushort)w8[j]);
    }
    midr0[n] = gelu_exact(acc + b11[n]);
}

__global__ __launch_bounds__(256)
void tail_ffn2_kernel(const float* __restrict__ midr0, const ushort* __restrict__ W21t,
                      const float* __restrict__ b21, float* __restrict__ h)
{
    __shared__ float ms[1024];
    const int tid = threadIdx.x;
    for (int i = tid; i < 1024; i += 256) ms[i] = midr0[i];
    __syncthreads();
    const int n  = blockIdx.x * 64 + (tid >> 2);
    const int kq = (tid & 3) * 256;
    float acc = 0.f;
    for (int k2 = 0; k2 < 256; k2 += 8) {
        const short8 w8 = *(const short8*)&W21t[(size_t)n * 1024 + kq + k2];
        #pragma unroll
        for (int j = 0; j < 8; ++j) acc += ms[kq + k2 + j] * bf2f((ushort)w8[j]);
    }
    acc += __shfl_xor(acc, 1);
    acc += __shfl_xor(acc, 2);
    if ((tid & 3) == 0) h[n] = h[n] + acc + b21[n];
}

__global__ __launch_bounds__(256)
void tail_final_kernel(const float* __restrict__ h, const float* __restrict__ eg,
                       const float* __restrict__ eb, const float* __restrict__ ng,
                       const float* __restrict__ nb, float* __restrict__ out)
{
    __shared__ float red[4];
    const int d = threadIdx.x;
    float xv = h[d];
    {
        const float mu = block_sum256(xv, red) * (1.0f / 256.0f);
        const float dv = xv - mu;
        const float var = block_sum256(dv * dv, red) * (1.0f / 256.0f);
        xv = dv * rsqrtf(var + 1e-5f) * eg[d] + eb[d];
    }
    {
        const float mu = block_sum256(xv, red) * (1.0f / 256.0f);
        const float dv = xv - mu;
        const float var = block_sum256(dv * dv, red) * (1.0f / 256.0f);
        out[d] = dv * rsqrtf(var + 1e-5f) * ng[d] + nb[d];
    }
}

extern "C" void kernel_launch(void* const* d_in, const int* in_sizes, int n_in,
                              void* d_out, int out_size, void* d_ws, size_t ws_size,
                              hipStream_t stream)
{
    const float* x      = (const float*)d_in[0];
    const int*   coords = (const int*)  d_in[1];
    const float* proj_w = (const float*)d_in[2];
    const float* proj_b = (const float*)d_in[3];
    const float* cls_tok= (const float*)d_in[4];
    const float* Wq     = (const float*)d_in[5];
    const float* Wk     = (const float*)d_in[6];
    const float* Wv     = (const float*)d_in[7];
    const float* Wo     = (const float*)d_in[8];
    const float* bq     = (const float*)d_in[9];
    const float* bk     = (const float*)d_in[10];
    const float* bv     = (const float*)d_in[11];
    const float* bo_    = (const float*)d_in[12];
    const float* ln1_g  = (const float*)d_in[13];
    const float* ln1_b  = (const float*)d_in[14];
    const float* ln2_g  = (const float*)d_in[15];
    const float* ln2_b  = (const float*)d_in[16];
    const float* W1     = (const float*)d_in[17];
    const float* b1     = (const float*)d_in[18];
    const float* W2     = (const float*)d_in[19];
    const float* b2v    = (const float*)d_in[20];
    const float* enc_g  = (const float*)d_in[21];
    const float* enc_b  = (const float*)d_in[22];
    const float* norm_g = (const float*)d_in[23];
    const float* norm_b = (const float*)d_in[24];
    float* out = (float*)d_out;

    const size_t SD = (size_t)S_TOT * DD;      // 2,097,152
    float* ws   = (float*)d_ws;
    float* h    = ws;                          // SD fp32
    float* big  = h + SD;                      // 5*SD fp32: bo5 | xbf | midbf overlay
    float* bo5  = big;
    ushort* xbf   = (ushort*)big;              // 8191*1536 ushort
    ushort* midbf = (ushort*)big;              // 8192*1024 ushort
    float* lse5 = big + 5 * SD;                // 327,680 fp32
    ushort* a_bf    = (ushort*)(lse5 + 5 * S_TOT * NHEAD);   // SD ushort
    ushort* qkv_bf  = a_bf + SD;               // 3*SD ushort
    ushort* attn_bf = qkv_bf + 3 * SD;         // SD ushort
    ushort* wbuf    = attn_bf + SD;            // WBUF_TOT ushort
    float* bqkv0  = (float*)(wbuf + WBUF_TOT); // 768
    float* bkv1   = bqkv0 + 768;               // 512
    float* qrow0  = bkv1 + 512;                // 256
    float* f_r0   = qrow0 + 256;               // 256
    float* midr0  = f_r0 + 256;                // 1024

    auto gemm3 = [&](const ushort* A, const ushort* Bt, const float* bias, void* C,
                     int M, int N, int K, int flags) {
        gemm3_kernel<<<64 * (N / 64), 256, 0, stream>>>(A, Bt, bias, C, M, N, K,
                                                        flags, coords);
    };

    // ---- setup ----
    setup_kernel<<<6627, 256, 0, stream>>>(x, proj_w, Wq, Wk, Wv, Wo, W1, W2,
                                           bq, bk, bv, cls_tok, wbuf, bqkv0, bkv1,
                                           xbf, h);

    // ---- projection (+ fused pos-embed) ----
    gemm3(xbf, wbuf + OFF_PROJ, proj_b, h + DD, 8191, 256, 1536, 8);

    // ---- layer 0 ----
    ln_kernel<<<S_TOT, 256, 0, stream>>>(h, ln1_g, ln1_b, a_bf);
    gemm3(a_bf, wbuf + OFF_WQ0, bqkv0, qkv_bf, 8192, 768, 256, 4);       // QKV
    attn_mfma_kernel<<<dim3(128, 8), 256, 0, stream>>>(qkv_bf, qkv_bf + 256,
                                                       qkv_bf + 512, bo5, lse5, 768);
    combine_kernel<<<S_TOT, 256, 0, stream>>>(bo5, lse5, attn_bf);
    gemm3(attn_bf, wbuf + OFF_WO0, bo_, h, 8192, 256, 256, 1);           // Wo, acc
    ln_kernel<<<S_TOT, 256, 0, stream>>>(h, ln2_g, ln2_b, a_bf);
    gemm3(a_bf, wbuf + OFF_W10, b1, midbf, 8192, 1024, 256, 4 | 2);      // FFN1 gelu
    gemm3(midbf, wbuf + OFF_W20, b2v, h, 8192, 256, 1024, 1);            // FFN2, acc

    // ---- layer 1 (pruned) ----
    ln_kernel<<<S_TOT, 256, 0, stream>>>(h, ln1_g + 256, ln1_b + 256, a_bf);
    gemm3(a_bf, wbuf + OFF_WK1, bkv1, qkv_bf, 8192, 512, 256, 4);        // K,V
    tail_qrow_kernel<<<1, 256, 0, stream>>>(h, ln1_g + 256, ln1_b + 256,
                                            wbuf + OFF_WQ1, bq + 256, qrow0);
    attn_row0_kernel<<<40, 64, 0, stream>>>(qrow0, qkv_bf, qkv_bf + 256, bo5, lse5, 512);
    tail_mid_kernel<<<1, 256, 0, stream>>>(bo5, lse5, h, wbuf + OFF_WO1, bo_ + 256,
                                           ln2_g + 256, ln2_b + 256, f_r0);
    tail_ffn1_kernel<<<4, 256, 0, stream>>>(f_r0, wbuf + OFF_W11, b1 + 1024, midr0);
    tail_ffn2_kernel<<<4, 256, 0, stream>>>(midr0, wbuf + OFF_W21, b2v + 256, h);
    tail_final_kernel<<<1, 256, 0, stream>>>(h, enc_g, enc_b, norm_g, norm_b, out);
}

// Round 11
// 475.111 us; speedup vs baseline: 1.0927x; 1.0927x over previous
//
#include <hip/hip_runtime.h>
#include <math.h>

#define S_TOT 8192
#define DD 256
#define NHEAD 8
#define HDSZ 32
#define ATT_SCALE 0.17677669529663687f
#define ATT_SCALE_LOG2E 0.25506601f   // ATT_SCALE * log2(e)

typedef short short8 __attribute__((ext_vector_type(8)));
typedef float f32x4 __attribute__((ext_vector_type(4)));
typedef unsigned short ushort;

// wbuf offsets (ushort elements)
#define OFF_PROJ 0
#define OFF_WQ0  393216
#define OFF_WK0  458752
#define OFF_WV0  524288
#define OFF_WO0  589824
#define OFF_W10  655360
#define OFF_W20  917504
#define OFF_WK1  1179648
#define OFF_WV1  1245184
#define OFF_WQ1  1310720
#define OFF_WO1  1376256
#define OFF_W11  1441792
#define OFF_W21  1703936
#define WBUF_TOT 1966080

__device__ inline ushort f2bf(float f) {
    union { float f; unsigned u; } c; c.f = f;
    unsigned u = c.u;
    u += 0x7fffu + ((u >> 16) & 1u);          // RNE
    return (ushort)(u >> 16);
}
__device__ inline float bf2f(ushort u) {
    union { unsigned u; float f; } c; c.u = ((unsigned)u) << 16;
    return c.f;
}
__device__ inline float gelu_exact(float v) {
    return 0.5f * v * (1.0f + erff(v * 0.7071067811865475f));
}
__device__ inline float block_sum256(float v, float* red) {
    #pragma unroll
    for (int off = 32; off > 0; off >>= 1) v += __shfl_down(v, off, 64);
    const int wid = threadIdx.x >> 6, lane = threadIdx.x & 63;
    if (lane == 0) red[wid] = v;
    __syncthreads();
    const float s = red[0] + red[1] + red[2] + red[3];
    __syncthreads();
    return s;
}

// ============ setup: weight transposes + bias concat + x->bf16 + cls ============
__global__ __launch_bounds__(256)
void setup_kernel(const float* __restrict__ x, const float* __restrict__ proj_w,
                  const float* __restrict__ Wq, const float* __restrict__ Wk,
                  const float* __restrict__ Wv, const float* __restrict__ Wo,
                  const float* __restrict__ W1, const float* __restrict__ W2,
                  const float* __restrict__ bq, const float* __restrict__ bk,
                  const float* __restrict__ bv, const float* __restrict__ cls_tok,
                  ushort* __restrict__ wbuf, float* __restrict__ bqkv0,
                  float* __restrict__ bkv1, ushort* __restrict__ xbf,
                  float* __restrict__ h)
{
    const int b = blockIdx.x;
    const int t = threadIdx.x;
    if (b >= 482) {
        if (b == 6626) { h[t] = cls_tok[t]; return; }   // cls (tab[0]==0)
        const int i = (b - 482) * 256 + t;
        const int n8 = 8191 * 1536 / 8;
        if (i >= n8) return;
        const float4 a0 = *(const float4*)(x + (size_t)i * 8);
        const float4 a1 = *(const float4*)(x + (size_t)i * 8 + 4);
        ushort tmp[8] = { f2bf(a0.x), f2bf(a0.y), f2bf(a0.z), f2bf(a0.w),
                          f2bf(a1.x), f2bf(a1.y), f2bf(a1.z), f2bf(a1.w) };
        *(uint4*)(xbf + (size_t)i * 8) = *(const uint4*)tmp;
        return;
    }
    if (b >= 480) {
        if (b == 480) {
            for (int i = t; i < 768; i += 256)
                bqkv0[i] = (i < 256) ? bq[i] : ((i < 512) ? bk[i - 256] : bv[i - 512]);
        } else {
            for (int i = t; i < 512; i += 256)
                bkv1[i] = (i < 256) ? bk[256 + i] : bv[i];
        }
        return;
    }
    const float* src; ushort* dst; int R, C, t0;
    if (b < 96)       { src = proj_w;        dst = wbuf + OFF_PROJ; R = 1536; C = 256;  t0 = 0;   }
    else if (b < 112) { src = Wq;            dst = wbuf + OFF_WQ0;  R = 256;  C = 256;  t0 = 96;  }
    else if (b < 128) { src = Wk;            dst = wbuf + OFF_WK0;  R = 256;  C = 256;  t0 = 112; }
    else if (b < 144) { src = Wv;            dst = wbuf + OFF_WV0;  R = 256;  C = 256;  t0 = 128; }
    else if (b < 160) { src = Wo;            dst = wbuf + OFF_WO0;  R = 256;  C = 256;  t0 = 144; }
    else if (b < 224) { src = W1;            dst = wbuf + OFF_W10;  R = 256;  C = 1024; t0 = 160; }
    else if (b < 288) { src = W2;            dst = wbuf + OFF_W20;  R = 1024; C = 256;  t0 = 224; }
    else if (b < 304) { src = Wk + 65536;    dst = wbuf + OFF_WK1;  R = 256;  C = 256;  t0 = 288; }
    else if (b < 320) { src = Wv + 65536;    dst = wbuf + OFF_WV1;  R = 256;  C = 256;  t0 = 304; }
    else if (b < 336) { src = Wq + 65536;    dst = wbuf + OFF_WQ1;  R = 256;  C = 256;  t0 = 320; }
    else if (b < 352) { src = Wo + 65536;    dst = wbuf + OFF_WO1;  R = 256;  C = 256;  t0 = 336; }
    else if (b < 416) { src = W1 + 262144;   dst = wbuf + OFF_W11;  R = 256;  C = 1024; t0 = 352; }
    else              { src = W2 + 262144;   dst = wbuf + OFF_W21;  R = 1024; C = 256;  t0 = 416; }
    const int lt = b - t0;
    const int tC = C >> 6;
    const int tr = lt / tC, tc = lt % tC;
    __shared__ ushort tile[64][68];
    const int col = t & 63;
    const int r4  = t >> 6;
    #pragma unroll
    for (int i = 0; i < 16; ++i) {
        const int row = i * 4 + r4;
        tile[row][col] = f2bf(src[(size_t)(tr * 64 + row) * C + tc * 64 + col]);
    }
    __syncthreads();
    #pragma unroll
    for (int i = 0; i < 16; ++i) {
        const int n = i * 4 + r4;
        dst[(size_t)(tc * 64 + n) * R + tr * 64 + col] = tile[col][n];
    }
}

// ============ LayerNorm over D=256, one block per row, bf16 out ============
__global__ __launch_bounds__(256)
void ln_kernel(const float* __restrict__ in, const float* __restrict__ g,
               const float* __restrict__ b, ushort* __restrict__ outp)
{
    __shared__ float red[4];
    const int row = blockIdx.x;
    const int d = threadIdx.x;
    const float xv = in[(size_t)row * DD + d];
    const float mu = block_sum256(xv, red) * (1.0f / 256.0f);
    const float dv = xv - mu;
    const float var = block_sum256(dv * dv, red) * (1.0f / 256.0f);
    outp[(size_t)row * DD + d] = f2bf(dv * rsqrtf(var + 1e-5f) * g[d] + b[d]);
}

// ============ gemm4: BM=64 x BN(template), BK=64, XCD-swizzled 1-D grid ============
// C = [C +] act(A @ Bt^T + bias) [+ pos].  A bf16 MxK, Bt bf16 NxK.
// 4 waves 2x2. BN=64: wave 32x32 (2x2 MFMA). BN=128: wave 32x64 (2x4 MFMA).
// flags: 1 = acc into fp32 C, 2 = GELU, 4 = bf16 out, 8 = pos-embed.
// grid = 128 * (N/BN) blocks (M_pad = 8192); slab count 128 divisible by 8.
template <int BN>
__global__ __launch_bounds__(256)
void gemm4_kernel(const ushort* __restrict__ A, const ushort* __restrict__ Bt,
                  const float* __restrict__ bias, void* __restrict__ Cv,
                  int M, int N, int K, int flags, const int* __restrict__ coords)
{
    __shared__ ushort As[64][72];
    __shared__ ushort Bs[BN][72];
    constexpr int NT = BN / 32;                // MFMA n-tiles per wave (2 or 4)
    const int nx  = N / BN;
    const int ny8 = gridDim.x / (8 * nx);      // m-slabs per XCD (=16)
    const int b   = blockIdx.x;
    const int c8  = b & 7;
    const int j   = b >> 3;
    const int m0  = (c8 * ny8 + j / nx) * 64;
    const int n0  = (j % nx) * BN;

    const int tid  = threadIdx.x;
    const int wave = tid >> 6;
    const int lane = tid & 63;
    const int lrow = lane & 15;
    const int quad = lane >> 4;
    const int wr = (wave >> 1) * 32;           // {0,32}
    const int wc = (wave & 1) * (BN / 2);      // {0,BN/2}

    float* Cf  = (float*)Cv;
    ushort* Cb = (ushort*)Cv;

    f32x4 acc[2][NT];
    #pragma unroll
    for (int mt = 0; mt < 2; ++mt)
        #pragma unroll
        for (int nt = 0; nt < NT; ++nt)
            acc[mt][nt] = (f32x4){0.f, 0.f, 0.f, 0.f};

    for (int kk = 0; kk < K; kk += 64) {
        #pragma unroll
        for (int i = 0; i < 2; ++i) {          // A: 64 rows x 64 cols
            const int idx = i * 256 + tid;
            const int r = idx >> 3;
            const int c = (idx & 7) * 8;
            const int gr = m0 + r;
            uint4 val = make_uint4(0u, 0u, 0u, 0u);
            if (gr < M) val = *(const uint4*)(A + (size_t)gr * K + kk + c);
            *(uint4*)&As[r][c] = val;
        }
        #pragma unroll
        for (int i = 0; i < BN / 32; ++i) {    // B: BN rows x 64 cols
            const int idx = i * 256 + tid;
            const int r = idx >> 3;
            const int c = (idx & 7) * 8;
            *(uint4*)&Bs[r][c] = *(const uint4*)(Bt + (size_t)(n0 + r) * K + kk + c);
        }
        __syncthreads();
        #pragma unroll
        for (int ks = 0; ks < 2; ++ks) {
            short8 af[2], bfr[NT];
            #pragma unroll
            for (int mt = 0; mt < 2; ++mt)
                af[mt] = *(const short8*)&As[wr + mt * 16 + lrow][ks * 32 + quad * 8];
            #pragma unroll
            for (int nt = 0; nt < NT; ++nt)
                bfr[nt] = *(const short8*)&Bs[wc + nt * 16 + lrow][ks * 32 + quad * 8];
            #pragma unroll
            for (int mt = 0; mt < 2; ++mt)
                #pragma unroll
                for (int nt = 0; nt < NT; ++nt)
                    acc[mt][nt] = __builtin_amdgcn_mfma_f32_16x16x32_bf16(
                                      af[mt], bfr[nt], acc[mt][nt], 0, 0, 0);
        }
        __syncthreads();
    }
    #pragma unroll
    for (int mt = 0; mt < 2; ++mt) {
        #pragma unroll
        for (int rg = 0; rg < 4; ++rg) {
            const int r = m0 + wr + mt * 16 + quad * 4 + rg;
            if (r >= M) continue;
            #pragma unroll
            for (int nt = 0; nt < NT; ++nt) {
                const int c = n0 + wc + nt * 16 + lrow;
                float vv = acc[mt][nt][rg] + bias[c];
                if (flags & 8) {   // pos-embed for token r (output = h row r+1)
                    const int cg = coords[2 * r + ((c < 128) ? 1 : 0)] >> 8;
                    const float omega = 1.0f / powf(10000.0f, (float)(c & 63) * (1.0f / 64.0f));
                    const float o = (float)cg * omega;
                    vv += ((c & 64) == 0) ? sinf(o) : cosf(o);
                }
                if (flags & 2) vv = gelu_exact(vv);
                if (flags & 4) {
                    Cb[(size_t)r * N + c] = f2bf(vv);
                } else {
                    if (flags & 1) vv += Cf[(size_t)r * N + c];
                    Cf[(size_t)r * N + c] = vv;
                }
            }
        }
    }
}

// ============ MFMA dilated attention (bf16, no-max softmax) ============
__global__ __launch_bounds__(256)
void attn_mfma_kernel(const ushort* __restrict__ q, const ushort* __restrict__ k,
                      const ushort* __restrict__ v, float* __restrict__ bo5,
                      float* __restrict__ lse5, int qs)
{
    __shared__ ushort Kb[64][40];
    __shared__ ushort Vt[32][72];
    __shared__ ushort Pb[4][16][72];

    const int unit = blockIdx.x;
    const int segu = unit >> 3;
    const int head = unit & 7;
    int b2, n;
    if (segu < 8)        { b2 = 0; n = segu; }
    else if (segu < 12)  { b2 = 1; n = segu - 8; }
    else if (segu < 14)  { b2 = 2; n = segu - 12; }
    else if (segu == 14) { b2 = 3; n = 0; }
    else                 { b2 = 4; n = 0; }
    const int w  = 1024 << b2;
    const int rr = 1 << b2;
    const int base = n * w + (head & (rr - 1));

    int kEnd = (S_TOT - base + rr - 1) >> b2;
    if (kEnd > 1024) kEnd = 1024;
    if (blockIdx.y * 128 >= kEnd) return;

    const int tid  = threadIdx.x;
    const int wave = tid >> 6;
    const int lane = tid & 63;
    const int lrow = lane & 15;
    const int quad = lane >> 4;

    short8 qf[2];
    #pragma unroll
    for (int m = 0; m < 2; ++m) {
        const int j  = blockIdx.y * 128 + wave * 32 + m * 16 + lrow;
        const int pq = base + rr * j;
        qf[m] = *(const short8*)(q + (size_t)pq * qs + head * HDSZ + quad * 8);
    }

    f32x4 acc[2][2];
    float lsum[2][4];
    #pragma unroll
    for (int m = 0; m < 2; ++m) {
        #pragma unroll
        for (int dt = 0; dt < 2; ++dt) acc[m][dt] = (f32x4){0.f, 0.f, 0.f, 0.f};
        #pragma unroll
        for (int rg = 0; rg < 4; ++rg) lsum[m][rg] = 0.f;
    }

    const int skr = tid >> 2;          // 0..63
    const int sdb = (tid & 3) * 8;     // 0,8,16,24

    for (int kc = 0; kc < kEnd; kc += 64) {
        {
            const size_t prow = (size_t)(base + rr * (kc + skr)) * qs + head * HDSZ + sdb;
            *(uint4*)&Kb[skr][sdb] = *(const uint4*)(k + prow);
            const uint4 vv = *(const uint4*)(v + prow);
            const ushort* vp = (const ushort*)&vv;
            #pragma unroll
            for (int i = 0; i < 8; ++i) Vt[sdb + i][skr] = vp[i];   // static index
        }
        __syncthreads();

        short8 kf[4], vf[2][2];
        #pragma unroll
        for (int t = 0; t < 4; ++t)
            kf[t] = *(const short8*)&Kb[t * 16 + lrow][quad * 8];
        #pragma unroll
        for (int g = 0; g < 2; ++g)
            #pragma unroll
            for (int dt = 0; dt < 2; ++dt)
                vf[g][dt] = *(const short8*)&Vt[dt * 16 + lrow][g * 32 + quad * 8];

        #pragma unroll
        for (int m = 0; m < 2; ++m) {
            f32x4 sc[4];
            #pragma unroll
            for (int t = 0; t < 4; ++t)
                sc[t] = __builtin_amdgcn_mfma_f32_16x16x32_bf16(
                            qf[m], kf[t], (f32x4){0.f,0.f,0.f,0.f}, 0, 0, 0);
            float p[4][4];
            #pragma unroll
            for (int t = 0; t < 4; ++t)
                #pragma unroll
                for (int rg = 0; rg < 4; ++rg)
                    p[t][rg] = exp2f(sc[t][rg] * ATT_SCALE_LOG2E);
            #pragma unroll
            for (int rg = 0; rg < 4; ++rg)
                lsum[m][rg] += (p[0][rg] + p[1][rg]) + (p[2][rg] + p[3][rg]);
            #pragma unroll
            for (int t = 0; t < 4; ++t)
                #pragma unroll
                for (int rg = 0; rg < 4; ++rg)
                    Pb[wave][quad * 4 + rg][t * 16 + lrow] = f2bf(p[t][rg]);
            __threadfence_block();
            short8 pa[2];
            #pragma unroll
            for (int g = 0; g < 2; ++g)
                pa[g] = *(const short8*)&Pb[wave][lrow][g * 32 + quad * 8];
            #pragma unroll
            for (int g = 0; g < 2; ++g)
                #pragma unroll
                for (int dt = 0; dt < 2; ++dt)
                    acc[m][dt] = __builtin_amdgcn_mfma_f32_16x16x32_bf16(
                                     pa[g], vf[g][dt], acc[m][dt], 0, 0, 0);
        }
        __syncthreads();
    }

    #pragma unroll
    for (int m = 0; m < 2; ++m) {
        #pragma unroll
        for (int rg = 0; rg < 4; ++rg) {
            float li = lsum[m][rg];
            #pragma unroll
            for (int off = 1; off < 16; off <<= 1)
                li += __shfl_xor(li, off, 16);
            const int j  = blockIdx.y * 128 + wave * 32 + m * 16 + quad * 4 + rg;
            const int pq = base + rr * j;
            const float inv = 1.0f / li;
            float* dst = bo5 + ((size_t)b2 * S_TOT + pq) * DD + head * HDSZ;
            dst[lrow]      = acc[m][0][rg] * inv;
            dst[16 + lrow] = acc[m][1][rg] * inv;
            if (lrow == 0)
                lse5[((size_t)b2 * S_TOT + pq) * NHEAD + head] = __logf(li);
        }
    }
}

// ============ layer-1 pruned attention: query position 0 only ============
__global__ __launch_bounds__(64)
void attn_row0_kernel(const float* __restrict__ q, const ushort* __restrict__ k,
                      const ushort* __restrict__ v, float* __restrict__ bo5,
                      float* __restrict__ lse5, int kvs)
{
    const int b2 = blockIdx.x >> 3;
    const int head = blockIdx.x & 7;
    const int r = 1 << b2;
    if (head & (r - 1)) return;
    const int tid = threadIdx.x;
    float qreg[32];
    #pragma unroll
    for (int d = 0; d < 32; d += 4) {
        const float4 t4 = *(const float4*)(q + head * HDSZ + d);
        qreg[d] = t4.x; qreg[d+1] = t4.y; qreg[d+2] = t4.z; qreg[d+3] = t4.w;
    }
    float m = -3.0e38f, l = 0.f, o[32];
    #pragma unroll
    for (int d = 0; d < 32; ++d) o[d] = 0.f;
    for (int j = tid; j < 1024; j += 64) {
        const int pk = r * j;
        float s;
        if (pk < S_TOT) {
            float s0 = 0.f;
            #pragma unroll
            for (int d = 0; d < 32; d += 8) {
                const uint4 raw = *(const uint4*)(k + (size_t)pk * kvs + head * HDSZ + d);
                const ushort* kp = (const ushort*)&raw;
                #pragma unroll
                for (int i = 0; i < 8; ++i) s0 += qreg[d + i] * bf2f(kp[i]);
            }
            s = s0 * ATT_SCALE;
        } else s = -1.0e9f;
        const float mn = fmaxf(m, s);
        const float c = __expf(m - mn);
        const float e = __expf(s - mn);
        l = l * c + e; m = mn;
        if (pk < S_TOT) {
            #pragma unroll
            for (int d = 0; d < 32; d += 8) {
                const uint4 raw = *(const uint4*)(v + (size_t)pk * kvs + head * HDSZ + d);
                const ushort* vp = (const ushort*)&raw;
                #pragma unroll
                for (int i = 0; i < 8; ++i) o[d + i] = o[d + i] * c + e * bf2f(vp[i]);
            }
        } else {
            #pragma unroll
            for (int d = 0; d < 32; ++d) o[d] *= c;
        }
    }
    __shared__ float ms[64], ls[64], os[64][32];
    ms[tid] = m; ls[tid] = l;
    #pragma unroll
    for (int d = 0; d < 32; ++d) os[tid][d] = o[d];
    __syncthreads();
    for (int st = 32; st >= 1; st >>= 1) {
        if (tid < st) {
            const float m2 = ms[tid + st], l2 = ls[tid + st];
            const float mn = fmaxf(ms[tid], m2);
            const float c1 = __expf(ms[tid] - mn);
            const float c2 = __expf(m2 - mn);
            ls[tid] = ls[tid] * c1 + l2 * c2;
            ms[tid] = mn;
            for (int d = 0; d < 32; ++d) os[tid][d] = os[tid][d]*c1 + os[tid+st][d]*c2;
        }
        __syncthreads();
    }
    if (tid < 32) bo5[(size_t)b2 * S_TOT * DD + head * HDSZ + tid] = os[0][tid] / ls[0];
    if (tid == 0) lse5[(size_t)b2 * S_TOT * NHEAD + head] = ms[0] + __logf(ls[0]);
}

// ============ combine 5 branches (layer 0), bf16 out ============
__global__ __launch_bounds__(256)
void combine_kernel(const float* __restrict__ bo5, const float* __restrict__ lse5,
                    ushort* __restrict__ attn)
{
    const int p = blockIdx.x;
    const int d = threadIdx.x;
    const int h = d >> 5;
    float lse[5];
    bool sel[5];
    float mx = -3.0e38f;
    #pragma unroll
    for (int b2 = 0; b2 < 5; ++b2) {
        const int r = 1 << b2;
        sel[b2] = ((p & (r - 1)) == (h & (r - 1)));
        if (sel[b2]) {
            lse[b2] = lse5[((size_t)b2 * S_TOT + p) * NHEAD + h];
            mx = fmaxf(mx, lse[b2]);
        }
    }
    float wsum = 0.f, acc = 0.f;
    #pragma unroll
    for (int b2 = 0; b2 < 5; ++b2) {
        if (sel[b2]) {
            const float wgt = __expf(lse[b2] - mx);
            wsum += wgt;
            acc += wgt * bo5[((size_t)b2 * S_TOT + p) * DD + d];
        }
    }
    attn[(size_t)p * DD + d] = f2bf(acc / wsum);
}

// ============ tail kernels (row 0 only) ============
__global__ __launch_bounds__(256)
void tail_qrow_kernel(const float* __restrict__ h, const float* __restrict__ g,
                      const float* __restrict__ b, const ushort* __restrict__ Wt,
                      const float* __restrict__ bias, float* __restrict__ qrow0)
{
    __shared__ float red[4];
    __shared__ float as[256];
    const int d = threadIdx.x;
    const float xv = h[d];
    const float mu = block_sum256(xv, red) * (1.0f / 256.0f);
    const float dv = xv - mu;
    const float var = block_sum256(dv * dv, red) * (1.0f / 256.0f);
    as[d] = dv * rsqrtf(var + 1e-5f) * g[d] + b[d];
    __syncthreads();
    float acc = 0.f;
    for (int k2 = 0; k2 < 256; k2 += 8) {
        const short8 w8 = *(const short8*)&Wt[(size_t)d * 256 + k2];
        #pragma unroll
        for (int j = 0; j < 8; ++j) acc += as[k2 + j] * bf2f((ushort)w8[j]);
    }
    qrow0[d] = acc + bias[d];
}

__global__ __launch_bounds__(256)
void tail_mid_kernel(const float* __restrict__ bo5, const float* __restrict__ lse5,
                     float* __restrict__ h, const ushort* __restrict__ Wo1t,
                     const float* __restrict__ bo1, const float* __restrict__ g2,
                     const float* __restrict__ b2, float* __restrict__ f)
{
    __shared__ float red[4];
    __shared__ float att[256];
    const int d = threadIdx.x;
    const int hh = d >> 5;
    float lse[5]; bool sel[5]; float mx = -3.0e38f;
    #pragma unroll
    for (int bb = 0; bb < 5; ++bb) {
        const int r = 1 << bb;
        sel[bb] = ((hh & (r - 1)) == 0);
        if (sel[bb]) {
            lse[bb] = lse5[(size_t)bb * S_TOT * NHEAD + hh];
            mx = fmaxf(mx, lse[bb]);
        }
    }
    float wsum = 0.f, acc = 0.f;
    #pragma unroll
    for (int bb = 0; bb < 5; ++bb) {
        if (sel[bb]) {
            const float wgt = __expf(lse[bb] - mx);
            wsum += wgt;
            acc += wgt * bo5[(size_t)bb * S_TOT * DD + d];
        }
    }
    att[d] = acc / wsum;
    __syncthreads();
    float a2 = 0.f;
    for (int k2 = 0; k2 < 256; k2 += 8) {
        const short8 w8 = *(const short8*)&Wo1t[(size_t)d * 256 + k2];
        #pragma unroll
        for (int j = 0; j < 8; ++j) a2 += att[k2 + j] * bf2f((ushort)w8[j]);
    }
    const float hv = a2 + bo1[d] + h[d];
    h[d] = hv;
    const float mu = block_sum256(hv, red) * (1.0f / 256.0f);
    const float dv = hv - mu;
    const float var = block_sum256(dv * dv, red) * (1.0f / 256.0f);
    f[d] = dv * rsqrtf(var + 1e-5f) * g2[d] + b2[d];
}

__global__ __launch_bounds__(256)
void tail_ffn1_kernel(const float* __restrict__ f, const ushort* __restrict__ W11t,
                      const float* __restrict__ b11, float* __restrict__ midr0)
{
    __shared__ float fs[256];
    const int tid = threadIdx.x;
    fs[tid] = f[tid];
    __syncthreads();
    const int n = blockIdx.x * 256 + tid;
    float acc = 0.f;
    for (int k2 = 0; k2 < 256; k2 += 8) {
        const short8 w8 = *(const short8*)&W11t[(size_t)n * 256 + k2];
        #pragma unroll
        for (int j = 0; j < 8; ++j) acc += fs[k2 + j] * bf2f((ushort)w8[j]);
    }
    midr0[n] = gelu_exact(acc + b11[n]);
}

__global__ __launch_bounds__(256)
void tail_ffn2_kernel(const float* __restrict__ midr0, const ushort* __restrict__ W21t,
                      const float* __restrict__ b21, float* __restrict__ h)
{
    __shared__ float ms[1024];
    const int tid = threadIdx.x;
    for (int i = tid; i < 1024; i += 256) ms[i] = midr0[i];
    __syncthreads();
    const int n  = blockIdx.x * 64 + (tid >> 2);
    const int kq = (tid & 3) * 256;
    float acc = 0.f;
    for (int k2 = 0; k2 < 256; k2 += 8) {
        const short8 w8 = *(const short8*)&W21t[(size_t)n * 1024 + kq + k2];
        #pragma unroll
        for (int j = 0; j < 8; ++j) acc += ms[kq + k2 + j] * bf2f((ushort)w8[j]);
    }
    acc += __shfl_xor(acc, 1);
    acc += __shfl_xor(acc, 2);
    if ((tid & 3) == 0) h[n] = h[n] + acc + b21[n];
}

__global__ __launch_bounds__(256)
void tail_final_kernel(const float* __restrict__ h, const float* __restrict__ eg,
                       const float* __restrict__ eb, const float* __restrict__ ng,
                       const float* __restrict__ nb, float* __restrict__ out)
{
    __shared__ float red[4];
    const int d = threadIdx.x;
    float xv = h[d];
    {
        const float mu = block_sum256(xv, red) * (1.0f / 256.0f);
        const float dv = xv - mu;
        const float var = block_sum256(dv * dv, red) * (1.0f / 256.0f);
        xv = dv * rsqrtf(var + 1e-5f) * eg[d] + eb[d];
    }
    {
        const float mu = block_sum256(xv, red) * (1.0f / 256.0f);
        const float dv = xv - mu;
        const float var = block_sum256(dv * dv, red) * (1.0f / 256.0f);
        out[d] = dv * rsqrtf(var + 1e-5f) * ng[d] + nb[d];
    }
}

extern "C" void kernel_launch(void* const* d_in, const int* in_sizes, int n_in,
                              void* d_out, int out_size, void* d_ws, size_t ws_size,
                              hipStream_t stream)
{
    const float* x      = (const float*)d_in[0];
    const int*   coords = (const int*)  d_in[1];
    const float* proj_w = (const float*)d_in[2];
    const float* proj_b = (const float*)d_in[3];
    const float* cls_tok= (const float*)d_in[4];
    const float* Wq     = (const float*)d_in[5];
    const float* Wk     = (const float*)d_in[6];
    const float* Wv     = (const float*)d_in[7];
    const float* Wo     = (const float*)d_in[8];
    const float* bq     = (const float*)d_in[9];
    const float* bk     = (const float*)d_in[10];
    const float* bv     = (const float*)d_in[11];
    const float* bo_    = (const float*)d_in[12];
    const float* ln1_g  = (const float*)d_in[13];
    const float* ln1_b  = (const float*)d_in[14];
    const float* ln2_g  = (const float*)d_in[15];
    const float* ln2_b  = (const float*)d_in[16];
    const float* W1     = (const float*)d_in[17];
    const float* b1     = (const float*)d_in[18];
    const float* W2     = (const float*)d_in[19];
    const float* b2v    = (const float*)d_in[20];
    const float* enc_g  = (const float*)d_in[21];
    const float* enc_b  = (const float*)d_in[22];
    const float* norm_g = (const float*)d_in[23];
    const float* norm_b = (const float*)d_in[24];
    float* out = (float*)d_out;

    const size_t SD = (size_t)S_TOT * DD;      // 2,097,152
    float* ws   = (float*)d_ws;
    float* h    = ws;                          // SD fp32
    float* big  = h + SD;                      // 5*SD fp32: bo5 | xbf | midbf overlay
    float* bo5  = big;
    ushort* xbf   = (ushort*)big;              // 8191*1536 ushort
    ushort* midbf = (ushort*)big;              // 8192*1024 ushort
    float* lse5 = big + 5 * SD;                // 327,680 fp32
    ushort* a_bf    = (ushort*)(lse5 + 5 * S_TOT * NHEAD);   // SD ushort
    ushort* qkv_bf  = a_bf + SD;               // 3*SD ushort
    ushort* attn_bf = qkv_bf + 3 * SD;         // SD ushort
    ushort* wbuf    = attn_bf + SD;            // WBUF_TOT ushort
    float* bqkv0  = (float*)(wbuf + WBUF_TOT); // 768
    float* bkv1   = bqkv0 + 768;               // 512
    float* qrow0  = bkv1 + 512;                // 256
    float* f_r0   = qrow0 + 256;               // 256
    float* midr0  = f_r0 + 256;                // 1024

    auto gemm64 = [&](const ushort* A, const ushort* Bt, const float* bias, void* C,
                      int M, int N, int K, int flags) {
        gemm4_kernel<64><<<128 * (N / 64), 256, 0, stream>>>(A, Bt, bias, C, M, N, K,
                                                             flags, coords);
    };
    auto gemm128 = [&](const ushort* A, const ushort* Bt, const float* bias, void* C,
                       int M, int N, int K, int flags) {
        gemm4_kernel<128><<<128 * (N / 128), 256, 0, stream>>>(A, Bt, bias, C, M, N, K,
                                                               flags, coords);
    };

    // ---- setup ----
    setup_kernel<<<6627, 256, 0, stream>>>(x, proj_w, Wq, Wk, Wv, Wo, W1, W2,
                                           bq, bk, bv, cls_tok, wbuf, bqkv0, bkv1,
                                           xbf, h);

    // ---- projection (+ fused pos-embed) ----
    gemm64(xbf, wbuf + OFF_PROJ, proj_b, h + DD, 8191, 256, 1536, 8);

    // ---- layer 0 ----
    ln_kernel<<<S_TOT, 256, 0, stream>>>(h, ln1_g, ln1_b, a_bf);
    gemm128(a_bf, wbuf + OFF_WQ0, bqkv0, qkv_bf, 8192, 768, 256, 4);     // QKV
    attn_mfma_kernel<<<dim3(128, 8), 256, 0, stream>>>(qkv_bf, qkv_bf + 256,
                                                       qkv_bf + 512, bo5, lse5, 768);
    combine_kernel<<<S_TOT, 256, 0, stream>>>(bo5, lse5, attn_bf);
    gemm64(attn_bf, wbuf + OFF_WO0, bo_, h, 8192, 256, 256, 1);          // Wo, acc
    ln_kernel<<<S_TOT, 256, 0, stream>>>(h, ln2_g, ln2_b, a_bf);
    gemm128(a_bf, wbuf + OFF_W10, b1, midbf, 8192, 1024, 256, 4 | 2);    // FFN1 gelu
    gemm64(midbf, wbuf + OFF_W20, b2v, h, 8192, 256, 1024, 1);           // FFN2, acc

    // ---- layer 1 (pruned) ----
    ln_kernel<<<S_TOT, 256, 0, stream>>>(h, ln1_g + 256, ln1_b + 256, a_bf);
    gemm128(a_bf, wbuf + OFF_WK1, bkv1, qkv_bf, 8192, 512, 256, 4);      // K,V
    tail_qrow_kernel<<<1, 256, 0, stream>>>(h, ln1_g + 256, ln1_b + 256,
                                            wbuf + OFF_WQ1, bq + 256, qrow0);
    attn_row0_kernel<<<40, 64, 0, stream>>>(qrow0, qkv_bf, qkv_bf + 256, bo5, lse5, 512);
    tail_mid_kernel<<<1, 256, 0, stream>>>(bo5, lse5, h, wbuf + OFF_WO1, bo_ + 256,
                                           ln2_g + 256, ln2_b + 256, f_r0);
    tail_ffn1_kernel<<<4, 256, 0, stream>>>(f_r0, wbuf + OFF_W11, b1 + 1024, midr0);
    tail_ffn2_kernel<<<4, 256, 0, stream>>>(midr0, wbuf + OFF_W21, b2v + 256, h);
    tail_final_kernel<<<1, 256, 0, stream>>>(h, enc_g, enc_b, norm_g, norm_b, out);
}